// Round 9
// baseline (211.910 us; speedup 1.0000x reference)
//
#include <hip/hip_runtime.h>
#include <math.h>

#define N_TOK 4096
#define C_DIM 256
#define HEADS 8
#define HDIM  32
#define SCALE 0.17677669529663687f

typedef float f32x4 __attribute__((ext_vector_type(4)));
typedef float f32x2 __attribute__((ext_vector_type(2)));
typedef int   i32x4 __attribute__((ext_vector_type(4)));
typedef __bf16 bf16x8 __attribute__((ext_vector_type(8)));
typedef __bf16 bf16x2 __attribute__((ext_vector_type(2)));

#if defined(__has_builtin)
#if __has_builtin(__builtin_amdgcn_mfma_f32_16x16x32_bf16)
#define HAVE_MFMA_BUILTIN 1
#endif
#if __has_builtin(__builtin_amdgcn_fdot2_f32_bf16)
#define HAVE_DOT2 1
#endif
#endif

__device__ __forceinline__ unsigned short f2bf(float x){
  unsigned u = __float_as_uint(x);
  u += 0x7FFFu + ((u >> 16) & 1u);
  return (unsigned short)(u >> 16);
}

__device__ __forceinline__ float dot2bf(unsigned a, unsigned b, float c){
#ifdef HAVE_DOT2
  return __builtin_amdgcn_fdot2_f32_bf16(__builtin_bit_cast(bf16x2, a),
                                         __builtin_bit_cast(bf16x2, b), c, false);
#else
  c = fmaf(__uint_as_float(a << 16), __uint_as_float(b << 16), c);
  c = fmaf(__uint_as_float(a & 0xFFFF0000u), __uint_as_float(b & 0xFFFF0000u), c);
  return c;
#endif
}

// D = A(16x32) * B(32x16) + C via v_mfma_f32_16x16x32_bf16.
// A-frag: lane holds A[l&15][(l>>4)*8 + j]; B-frag: lane holds B[(l>>4)*8 + j][l&15]
// D: lane,reg r -> D[(l>>4)*4 + r][l&15]
__device__ __forceinline__ f32x4 mfma16(i32x4 a, i32x4 b, f32x4 c){
#ifdef HAVE_MFMA_BUILTIN
  return __builtin_amdgcn_mfma_f32_16x16x32_bf16(
      __builtin_bit_cast(bf16x8, a), __builtin_bit_cast(bf16x8, b), c, 0, 0, 0);
#else
  f32x4 d;
  asm volatile("v_mfma_f32_16x16x32_bf16 %0, %1, %2, %3\n\ts_nop 7\n\ts_nop 3"
               : "=&v"(d) : "v"(a), "v"(b), "v"(c));
  return d;
#endif
}

// ---------------- LayerNorm (one row of 256 per block) ----------------
template<int TO_BF>
__global__ __launch_bounds__(256) void ln_kernel(const float* __restrict__ x,
    const float* __restrict__ g, const float* __restrict__ b,
    float* __restrict__ outF, unsigned short* __restrict__ outB)
{
  int row = blockIdx.x, c = threadIdx.x;
  float v = x[(size_t)row*C_DIM + c];
  float s1 = v, s2 = v*v;
  #pragma unroll
  for (int off=1; off<64; off<<=1){
    s1 += __shfl_xor(s1, off);
    s2 += __shfl_xor(s2, off);
  }
  __shared__ float r1[4], r2[4];
  int wv = c >> 6;
  if ((c & 63) == 0){ r1[wv] = s1; r2[wv] = s2; }
  __syncthreads();
  s1 = r1[0]+r1[1]+r1[2]+r1[3];
  s2 = r2[0]+r2[1]+r2[2]+r2[3];
  float mu  = s1 * (1.0f/C_DIM);
  float var = s2 * (1.0f/C_DIM) - mu*mu;
  float inv = 1.0f / sqrtf(var + 1e-5f);
  float o = (v - mu) * inv * g[c] + b[c];
  if (TO_BF) outB[(size_t)row*C_DIM + c] = f2bf(o);
  else       outF[(size_t)row*C_DIM + c] = o;
}

// ---------------- 64x64 tiled transpose: src[R][C] -> dst[C][R] ----------------
__global__ __launch_bounds__(256) void transpose_k(const float* __restrict__ src,
    float* __restrict__ dstF, unsigned short* __restrict__ dstB, int R, int Cc)
{
  __shared__ float t[64][65];
  int c0 = blockIdx.x*64, r0 = blockIdx.y*64;
  int x = threadIdx.x & 63, ys = threadIdx.x >> 6;
  #pragma unroll
  for (int i=0;i<16;++i){
    int r = ys + i*4;
    t[r][x] = src[(size_t)(r0+r)*Cc + c0 + x];
  }
  __syncthreads();
  #pragma unroll
  for (int i=0;i<16;++i){
    int rr = ys + i*4;
    float val = t[x][rr];
    if (dstB) dstB[(size_t)(c0+rr)*R + r0 + x] = f2bf(val);
    else      dstF[(size_t)(c0+rr)*R + r0 + x] = val;
  }
}

__global__ void cvt_bf(const float* __restrict__ src, unsigned short* __restrict__ dst, int n){
  int i = blockIdx.x*256 + threadIdx.x;
  if (i < n) dst[i] = f2bf(src[i]);
}

// ---------------- repack K into MFMA-fragment order ----------------
__global__ __launch_bounds__(256) void repack_k(const unsigned short* __restrict__ kbf,
                                               unsigned short* __restrict__ kpack)
{
  int blk = blockIdx.x;          // h*256 + t
  int t = blk & 255, h = blk >> 8;
  int tid = threadIdx.x;
  int lane = tid >> 2;
  int j = (tid & 3) * 2;
  int l16 = lane & 15, lg = lane >> 4;
  unsigned val = *(const unsigned*)(kbf + (size_t)(t*16 + l16)*C_DIM + h*HDIM + lg*8 + j);
  *(unsigned*)(kpack + (size_t)blk*512 + tid*2) = val;
}

// ---------------- 16x32-wave GEMM (2 waves/block), optional split-K partials ----
template<int RELU>
__global__ __launch_bounds__(128) void gemm16x32(
    const unsigned short* __restrict__ A, const unsigned short* __restrict__ Wt,
    const float* __restrict__ bias, const float* __restrict__ resid,
    float* __restrict__ outF, unsigned short* __restrict__ outB,
    int K, int kchunk, float* __restrict__ pbuf)
{
  int wave = threadIdx.x >> 6, lane = threadIdx.x & 63;
  int l16 = lane & 15, lg = lane >> 4;
  int m0 = blockIdx.x*32 + wave*16;
  int n0 = blockIdx.y*32;
  int ks0 = blockIdx.z * kchunk;
  f32x4 acc0={0.f,0.f,0.f,0.f}, acc1=acc0;
  const unsigned short* ap  = A  + (size_t)(m0+l16)*K + ks0 + lg*8;
  const unsigned short* bp0 = Wt + (size_t)(n0   +l16)*K + ks0 + lg*8;
  const unsigned short* bp1 = Wt + (size_t)(n0+16+l16)*K + ks0 + lg*8;
  for (int ks = 0; ks < kchunk; ks += 32){
    i32x4 af = *(const i32x4*)(ap + ks);
    acc0 = mfma16(af, *(const i32x4*)(bp0 + ks), acc0);
    acc1 = mfma16(af, *(const i32x4*)(bp1 + ks), acc1);
  }
  if (pbuf){
    float* pb = pbuf + (size_t)blockIdx.z * (N_TOK*C_DIM);
    #pragma unroll
    for (int f=0; f<2; ++f){
      f32x4 acc = f ? acc1 : acc0;
      int n = n0 + f*16 + l16;
      #pragma unroll
      for (int r=0;r<4;++r)
        pb[(size_t)(m0 + lg*4 + r)*C_DIM + n] = acc[r];
    }
  } else {
    #pragma unroll
    for (int f=0; f<2; ++f){
      f32x4 acc = f ? acc1 : acc0;
      int n = n0 + f*16 + l16;
      float bb = bias[n];
      #pragma unroll
      for (int r=0;r<4;++r){
        int m = m0 + lg*4 + r;
        float val = acc[r] + bb;
        if (RELU) val = fmaxf(val, 0.0f);
        if (resid) val += resid[(size_t)m*C_DIM + n];
        if (outF) outF[(size_t)m*C_DIM + n] = val;
        if (outB) outB[(size_t)m*C_DIM + n] = f2bf(val);
      }
    }
  }
}

// ---------------- fused q/kv/v GEMM: Wt rows 0-255 q, 256-511 k, 512-767 v ----
__global__ __launch_bounds__(128) void gemm_qkv(
    const unsigned short* __restrict__ A, const unsigned short* __restrict__ Wt,
    const float* __restrict__ q_b, const float* __restrict__ kv_b,
    unsigned short* __restrict__ qbf, unsigned short* __restrict__ kbf,
    float* __restrict__ vbuf)
{
  int wave = threadIdx.x >> 6, lane = threadIdx.x & 63;
  int l16 = lane & 15, lg = lane >> 4;
  int m0 = blockIdx.x*32 + wave*16;
  int n0 = blockIdx.y*32;
  f32x4 acc0={0.f,0.f,0.f,0.f}, acc1=acc0;
  const unsigned short* ap  = A  + (size_t)(m0+l16)*C_DIM + lg*8;
  const unsigned short* bp0 = Wt + (size_t)(n0   +l16)*C_DIM + lg*8;
  const unsigned short* bp1 = Wt + (size_t)(n0+16+l16)*C_DIM + lg*8;
  for (int ks = 0; ks < C_DIM; ks += 32){
    i32x4 af = *(const i32x4*)(ap + ks);
    acc0 = mfma16(af, *(const i32x4*)(bp0 + ks), acc0);
    acc1 = mfma16(af, *(const i32x4*)(bp1 + ks), acc1);
  }
  #pragma unroll
  for (int f=0; f<2; ++f){
    f32x4 acc = f ? acc1 : acc0;
    int n = n0 + f*16 + l16;
    float bb = (n < 256) ? q_b[n] : kv_b[n-256];
    #pragma unroll
    for (int r=0;r<4;++r){
      int m = m0 + lg*4 + r;
      float val = acc[r] + bb;
      if (n < 256)      qbf[(size_t)m*C_DIM + n]        = f2bf(fmaxf(val, 0.f));
      else if (n < 512) kbf[(size_t)m*C_DIM + (n-256)]  = f2bf(val);
      else              vbuf[(size_t)m*C_DIM + (n-512)] = val;
    }
  }
}

// ---------------- split-K reduce: out = p0 + p1 + bias + resid ----------------
__global__ __launch_bounds__(256) void reduce_conv1(const float* __restrict__ pbuf,
    const float* __restrict__ bias, const float* __restrict__ resid,
    float* __restrict__ out)
{
  int i = (blockIdx.x*256 + threadIdx.x) * 4;
  f32x4 a = *(const f32x4*)(pbuf + i);
  f32x4 b = *(const f32x4*)(pbuf + (size_t)N_TOK*C_DIM + i);
  f32x4 r = *(const f32x4*)(resid + i);
  f32x4 bb = *(const f32x4*)(bias + (i & 255));
  *(f32x4*)(out + i) = a + b + r + bb;
}

// ---------------- column sum of v (for closed-form softmax) ----------------
__global__ __launch_bounds__(256) void colsum_part(const float* __restrict__ v, float* __restrict__ part){
  int b = blockIdx.x, c = threadIdx.x;
  float s = 0.f;
  for (int r=0;r<64;++r) s += v[(size_t)(b*64+r)*C_DIM + c];
  part[b*C_DIM + c] = s;
}
__global__ __launch_bounds__(256) void colsum_final(const float* __restrict__ part, float* __restrict__ sumv){
  int c = threadIdx.x;
  float s = 0.f;
  for (int b=0;b<64;++b) s += part[b*C_DIM + c];
  sumv[c] = s;
}

// ------- bitonic top-8 merge of sorted lists across xor-lane partners -------
#define CMPEX(A,I,i,j) { bool sw = (A[j] > A[i]) || (A[j]==A[i] && I[j]<I[i]); \
  float fv_ = sw?A[j]:A[i]; float sv_ = sw?A[i]:A[j]; \
  int fi_ = sw?I[j]:I[i]; int si_ = sw?I[i]:I[j]; \
  A[i]=fv_; A[j]=sv_; I[i]=fi_; I[j]=si_; }

template<int MLO, int MHI>
__device__ __forceinline__ void merge_lists(float (&tv)[8], int (&ti)[8]){
  #pragma unroll
  for (int m=MLO; m<=MHI; m<<=1){
    float ov[8]; int oi[8];
    #pragma unroll
    for (int j=0;j<8;++j){ ov[j] = __shfl_xor(tv[j], m); oi[j] = __shfl_xor(ti[j], m); }
    #pragma unroll
    for (int j=0;j<8;++j){
      float bv = ov[7-j]; int bi = oi[7-j];
      bool take = (bv > tv[j]) || (bv == tv[j] && bi < ti[j]);
      tv[j] = take?bv:tv[j]; ti[j] = take?bi:ti[j];
    }
    CMPEX(tv,ti,0,4) CMPEX(tv,ti,1,5) CMPEX(tv,ti,2,6) CMPEX(tv,ti,3,7)
    CMPEX(tv,ti,0,2) CMPEX(tv,ti,1,3) CMPEX(tv,ti,4,6) CMPEX(tv,ti,5,7)
    CMPEX(tv,ti,0,1) CMPEX(tv,ti,2,3) CMPEX(tv,ti,4,5) CMPEX(tv,ti,6,7)
  }
}

// block = 16 q-rows x 4 waves; wave w scans packed K-tiles [w*64, w*64+64) sequentially.
// Phase 1: lane-local 4-tile group maxes (16 cols), per-lane top-8, lane-group +
//          cross-wave merges. Phase 2: exact rescan of 8 groups (128 cols/row;
//          16 thr/row x 8 cols, v_dot2_bf16). Phase 3: closed-form softmax + PV.
__global__ __launch_bounds__(256, 8) void attn_kernel(
    const unsigned short* __restrict__ qbf, const unsigned short* __restrict__ kbf,
    const unsigned short* __restrict__ kpack,
    const float* __restrict__ v, const float* __restrict__ sumv,
    unsigned short* __restrict__ outbf)
{
  const int head = blockIdx.y;
  const int tid  = threadIdx.x;
  const int wave = tid >> 6, lane = tid & 63;
  const int l16 = lane & 15, lg = lane >> 4;
  const int row0 = blockIdx.x * 16;

  __shared__ float ls_v[4][16][8];
  __shared__ int   ls_i[4][16][8];
  __shared__ int   gsel[16][8];
  __shared__ float lds_e[16][8];
  __shared__ int   lds_idx[16][8];
  __shared__ float lds_d[16];

  // ---- phase 1: sequential packed-K MFMA scan, 4-tile group maxes ----
  i32x4 qf = *(const i32x4*)(qbf + (size_t)(row0 + l16)*C_DIM + head*HDIM + lg*8);
  const f32x4 zacc = {0.f,0.f,0.f,0.f};
  const int tbase = wave * 64;
  const unsigned short* kp = kpack + ((size_t)(head*256 + tbase)*64 + lane)*8;

  float tv[8]; int ti[8];
  #pragma unroll
  for (int j=0;j<8;++j){ tv[j]=-3e38f; ti[j]=0x7fffffff; }

  i32x4 kr0 = *(const i32x4*)(kp);
  i32x4 kr1 = *(const i32x4*)(kp + 512);
  i32x4 kr2 = *(const i32x4*)(kp + 1024);
  i32x4 kr3 = *(const i32x4*)(kp + 1536);
  for (int g = 0; g < 16; ++g){
    float gm = -3e38f;
    #pragma unroll
    for (int u = 0; u < 4; ++u){
      int t = g*4 + u;
      i32x4 cur = (u==0)?kr0 : (u==1)?kr1 : (u==2)?kr2 : kr3;
      f32x4 a0 = mfma16(cur, qf, zacc);
      i32x4 nxt = *(const i32x4*)(kp + (size_t)(t+4)*512);  // over-read (<=4KB) lands in qbf: safe
      if (u==0) kr0=nxt; else if (u==1) kr1=nxt; else if (u==2) kr2=nxt; else kr3=nxt;
      gm = fmaxf(gm, fmaxf(fmaxf(a0[0],a0[1]), fmaxf(a0[2],a0[3])));
    }
    if (gm > tv[7]){
      float cv = gm; int ci = (tbase + g*4)*16 + lg*4;   // group id = min col
      #pragma unroll
      for (int j=0;j<8;++j){
        bool gt = cv > tv[j];            // strict: ascending stream keeps earliest on tie
        float nv = gt?cv:tv[j]; float ov_ = gt?tv[j]:cv;
        int   ni = gt?ci:ti[j]; int   oi_ = gt?ti[j]:ci;
        tv[j]=nv; ti[j]=ni; cv=ov_; ci=oi_;
      }
    }
  }
  merge_lists<16,32>(tv, ti);   // per-row top-8 groups of this wave's chunk

  if (lg == 0){
    #pragma unroll
    for (int j=0;j<8;++j){ ls_v[wave][l16][j]=tv[j]; ls_i[wave][l16][j]=ti[j]; }
  }
  __syncthreads();

  if (wave == 0){
    float mv[8]; int mi[8];
    #pragma unroll
    for (int j=0;j<8;++j){ mv[j]=ls_v[lg][l16][j]; mi[j]=ls_i[lg][l16][j]; }
    merge_lists<16,32>(mv, mi);   // global top-8 groups per row
    if (lg == 0){
      #pragma unroll
      for (int j=0;j<8;++j) gsel[l16][j] = mi[j];
    }
  }
  __syncthreads();

  // ---- phase 2: exact rescan; 16 threads/row, 8 cols each (half a group) ----
  const int prow = tid >> 4;              // 0..15
  const int sub  = tid & 15;              // 0..15
  unsigned q2u[16];
  {
    const unsigned short* qrow = qbf + (size_t)(row0 + prow)*C_DIM + head*HDIM;
    #pragma unroll
    for (int i=0;i<4;++i){
      i32x4 qv = *(const i32x4*)(qrow + i*8);
      #pragma unroll
      for (int j=0;j<4;++j) q2u[i*4+j] = (unsigned)qv[j];
    }
  }
  int c0 = gsel[prow][sub >> 1];
  int ibase = (sub & 1) * 2;
  float sv[8]; int si[8];
  #pragma unroll
  for (int j=0;j<8;++j){ sv[j] = -3e38f; si[j] = 0x7fffffff; }
  #pragma unroll
  for (int ii=0; ii<2; ++ii){             // 2 tiles of the half-group
    #pragma unroll
    for (int rr=0; rr<4; ++rr){           // 4 cols per tile
      int col = c0 + 16*(ibase+ii) + rr;
      const unsigned short* krow = kbf + (size_t)col*C_DIM + head*HDIM;
      float s = 0.f;
      #pragma unroll
      for (int q=0;q<4;++q){
        i32x4 kv = *(const i32x4*)(krow + q*8);
        #pragma unroll
        for (int j=0;j<4;++j) s = dot2bf((unsigned)kv[j], q2u[q*4+j], s);
      }
      float cv = s; int ci = col;         // 8 candidates for top-8: insert unconditionally
      #pragma unroll
      for (int j=0;j<8;++j){
        bool gt = (cv > sv[j]) || (cv == sv[j] && ci < si[j]);
        float nv = gt?cv:sv[j]; float ov_ = gt?sv[j]:cv;
        int   ni = gt?ci:si[j]; int   oi_ = gt?si[j]:ci;
        sv[j]=nv; si[j]=ni; cv=ov_; ci=oi_;
      }
    }
  }
  merge_lists<1,8>(sv, si);               // exact top-8 elements per row

  if (sub == 0){
    float den = 4096.0f;
    #pragma unroll
    for (int j=0;j<8;++j){
      float e = expm1f(sv[j]*SCALE);
      den += e;
      lds_e[prow][j] = e;
      lds_idx[prow][j] = si[j];
    }
    lds_d[prow] = den;
  }
  __syncthreads();

  // ---- phase 3: closed-form masked softmax PV: 16 rows x 32 dims ----
  #pragma unroll
  for (int it=0; it<2; ++it){
    int flat = it*256 + tid;
    int rl = flat >> 5, d = flat & 31;
    float num = sumv[head*HDIM + d];
    float den = lds_d[rl];
    #pragma unroll
    for (int j=0;j<8;++j)
      num += lds_e[rl][j] * v[(size_t)lds_idx[rl][j]*C_DIM + head*HDIM + d];
    outbf[(size_t)(row0 + rl)*C_DIM + head*HDIM + d] = f2bf(num/den);
  }
}

// ---------------- LDS-tiled grouped dwconv 3x3 & 5x5 -> cat[p][2048] bf16 ----------------
__global__ __launch_bounds__(256) void dwconv_tiled(const float* __restrict__ img, // h2T [256][4096]
    const float* __restrict__ w3, const float* __restrict__ b3,
    const float* __restrict__ w5, const float* __restrict__ b5,
    unsigned short* __restrict__ cat)
{
  __shared__ float tile[8][513];
  int ic0 = blockIdx.x * 8;
  int py0 = blockIdx.y * 4;
  int tid = threadIdx.x;

  #pragma unroll
  for (int i = 0; i < 16; ++i){
    int idx = i*256 + tid;
    int ch  = idx >> 9;
    int rem = idx & 511;
    int ry  = rem >> 6, x = rem & 63;
    int y   = py0 - 2 + ry;
    float v = (y >= 0 && y < 64) ? img[(size_t)(ic0+ch)*4096 + y*64 + x] : 0.f;
    tile[ch][ry*64 + x] = v;
  }
  __syncthreads();

  int o_l  = tid & 31;
  int p_l  = tid >> 5;
  int ic_l = o_l >> 2;
  int o3   = ic0*4 + o_l;
  const float* pl = tile[ic_l];

  float W3[9], W5[25];
  #pragma unroll
  for (int i=0;i<9;++i)  W3[i] = w3[o3*9+i];
  #pragma unroll
  for (int i=0;i<25;++i) W5[i] = w5[o3*25+i];
  float bb3 = b3[o3], bb5 = b5[o3];

  #pragma unroll 4
  for (int it = 0; it < 32; ++it){
    int pp = it*8 + p_l;
    int ly = (pp >> 6) + 2;
    int x  = pp & 63;
    float a3 = bb3, a5 = bb5;
    #pragma unroll
    for (int dy=-2; dy<=2; ++dy){
      #pragma unroll
      for (int dx=-2; dx<=2; ++dx){
        int xx = x + dx;
        float iv = (xx >= 0 && xx < 64) ? pl[(ly+dy)*64 + xx] : 0.f;
        a5 += W5[(dy+2)*5 + dx+2] * iv;
        if (dy>=-1 && dy<=1 && dx>=-1 && dx<=1)
          a3 += W3[(dy+1)*3 + dx+1] * iv;
      }
    }
    int p = (py0 + (pp>>6))*64 + x;
    cat[(size_t)p*2048 + o3]        = f2bf(fmaxf(a3, 0.f));
    cat[(size_t)p*2048 + 1024 + o3] = f2bf(fmaxf(a5, 0.f));
  }
}

extern "C" void kernel_launch(void* const* d_in, const int* in_sizes, int n_in,
                              void* d_out, int out_size, void* d_ws, size_t ws_size,
                              hipStream_t stream)
{
  (void)in_sizes; (void)n_in; (void)out_size; (void)ws_size;
  const float* x      = (const float*)d_in[0];
  const float* ln1_g  = (const float*)d_in[3];
  const float* ln1_b  = (const float*)d_in[4];
  const float* q_w    = (const float*)d_in[5];
  const float* q_b    = (const float*)d_in[6];
  const float* kv_w   = (const float*)d_in[7];
  const float* kv_b   = (const float*)d_in[8];
  const float* proj_w = (const float*)d_in[9];
  const float* proj_b = (const float*)d_in[10];
  const float* ln2_g  = (const float*)d_in[11];
  const float* ln2_b  = (const float*)d_in[12];
  const float* w3     = (const float*)d_in[13];
  const float* b3     = (const float*)d_in[14];
  const float* w5     = (const float*)d_in[15];
  const float* b5     = (const float*)d_in[16];
  const float* w1     = (const float*)d_in[17];
  const float* b1     = (const float*)d_in[18];
  float* out = (float*)d_out;
  char* ws = (char*)d_ws;

  unsigned short* wAll = (unsigned short*)(ws + 0x0);       // 384 KB: q(256)|k,v(512) rows x 256
  unsigned short* pwT  = (unsigned short*)(ws + 0x60000);   // 128 KB
  unsigned short* w1bf = (unsigned short*)(ws + 0x80000);   // 1 MB
  unsigned short* hbf  = (unsigned short*)(ws + 0x180000);  // 2 MB
  unsigned short* qbf  = (unsigned short*)(ws + 0x380000);  // 2 MB
  unsigned short* kbf  = (unsigned short*)(ws + 0x580000);  // 2 MB
  float*          vbuf = (float*)(ws + 0x780000);           // 4 MB
  unsigned short* obf  = (unsigned short*)(ws + 0xB80000);  // 2 MB
  float*          x2   = (float*)(ws + 0xD80000);           // 4 MB
  float*          sumv = (float*)(ws + 0x1180000);          // 1 KB
  float*          part = (float*)(ws + 0x1190000);          // 64 KB
  unsigned short* kpack= (unsigned short*)(ws + 0x180000);  // 2 MB, reuse hbf (dead after qkv)
  float*          h2   = (float*)(ws + 0x180000);           // 4 MB, reuse hbf+qbf after attn
  float*          h2T  = (float*)(ws + 0x580000);           // 4 MB, reuse kbf+vbuf-lo after attn
  float*          pbuf = (float*)(ws + 0x180000);           // 8 MB, reuse h2/h2T after dwconv
  unsigned short* cat  = (unsigned short*)(ws + 0x1200000); // 16 MB -> end 0x2200000

  dim3 b256(256), b128(128);

  // weight prep
  cvt_bf<<<dim3(2048), b256, 0, stream>>>(w1, w1bf, 256*2048);
  transpose_k<<<dim3(4,4), b256, 0, stream>>>(q_w,   nullptr, wAll,  256, 256);
  transpose_k<<<dim3(8,4), b256, 0, stream>>>(kv_w,  nullptr, wAll + 256*256, 256, 512);
  transpose_k<<<dim3(4,4), b256, 0, stream>>>(proj_w,nullptr, pwT,  256, 256);

  // attention branch
  ln_kernel<1><<<dim3(4096), b256, 0, stream>>>(x, ln1_g, ln1_b, nullptr, hbf);
  gemm_qkv<<<dim3(128,24), b128, 0, stream>>>(hbf, wAll, q_b, kv_b, qbf, kbf, vbuf);
  repack_k<<<dim3(2048), b256, 0, stream>>>(kbf, kpack);    // overwrites hbf region (now dead)
  colsum_part <<<dim3(64), b256, 0, stream>>>(vbuf, part);
  colsum_final<<<dim3(1),  b256, 0, stream>>>(part, sumv);
  attn_kernel<<<dim3(256,8), b256, 0, stream>>>(qbf, kbf, kpack, vbuf, sumv, obf);
  gemm16x32<0><<<dim3(128,8,1), b128, 0, stream>>>(obf, pwT, proj_b, x, x2, nullptr, 256, 256, nullptr);

  // MSFN branch
  ln_kernel<0><<<dim3(4096), b256, 0, stream>>>(x2, ln2_g, ln2_b, h2, nullptr);
  transpose_k<<<dim3(4,64), b256, 0, stream>>>(h2, h2T, nullptr, 4096, 256);
  dwconv_tiled<<<dim3(32,16), b256, 0, stream>>>(h2T, w3, b3, w5, b5, cat);
  gemm16x32<0><<<dim3(128,8,2), b128, 0, stream>>>(cat, w1bf, nullptr, nullptr, nullptr, nullptr, 2048, 1024, pbuf);
  reduce_conv1<<<dim3(1024), b256, 0, stream>>>(pbuf, b1, x2, out);
}

// Round 10
// 206.501 us; speedup vs baseline: 1.0262x; 1.0262x over previous
//
#include <hip/hip_runtime.h>
#include <math.h>

#define N_TOK 4096
#define C_DIM 256
#define HEADS 8
#define HDIM  32
#define SCALE 0.17677669529663687f

typedef float f32x4 __attribute__((ext_vector_type(4)));
typedef float f32x2 __attribute__((ext_vector_type(2)));
typedef int   i32x4 __attribute__((ext_vector_type(4)));
typedef __bf16 bf16x8 __attribute__((ext_vector_type(8)));
typedef __bf16 bf16x2 __attribute__((ext_vector_type(2)));

#if defined(__has_builtin)
#if __has_builtin(__builtin_amdgcn_mfma_f32_16x16x32_bf16)
#define HAVE_MFMA_BUILTIN 1
#endif
#if __has_builtin(__builtin_amdgcn_fdot2_f32_bf16)
#define HAVE_DOT2 1
#endif
#endif

__device__ __forceinline__ unsigned short f2bf(float x){
  unsigned u = __float_as_uint(x);
  u += 0x7FFFu + ((u >> 16) & 1u);
  return (unsigned short)(u >> 16);
}

__device__ __forceinline__ float dot2bf(unsigned a, unsigned b, float c){
#ifdef HAVE_DOT2
  return __builtin_amdgcn_fdot2_f32_bf16(__builtin_bit_cast(bf16x2, a),
                                         __builtin_bit_cast(bf16x2, b), c, false);
#else
  c = fmaf(__uint_as_float(a << 16), __uint_as_float(b << 16), c);
  c = fmaf(__uint_as_float(a & 0xFFFF0000u), __uint_as_float(b & 0xFFFF0000u), c);
  return c;
#endif
}

// D = A(16x32) * B(32x16) + C via v_mfma_f32_16x16x32_bf16.
// A-frag: lane holds A[l&15][(l>>4)*8 + j]; B-frag: lane holds B[(l>>4)*8 + j][l&15]
// D: lane,reg r -> D[(l>>4)*4 + r][l&15]
__device__ __forceinline__ f32x4 mfma16(i32x4 a, i32x4 b, f32x4 c){
#ifdef HAVE_MFMA_BUILTIN
  return __builtin_amdgcn_mfma_f32_16x16x32_bf16(
      __builtin_bit_cast(bf16x8, a), __builtin_bit_cast(bf16x8, b), c, 0, 0, 0);
#else
  f32x4 d;
  asm volatile("v_mfma_f32_16x16x32_bf16 %0, %1, %2, %3\n\ts_nop 7\n\ts_nop 3"
               : "=&v"(d) : "v"(a), "v"(b), "v"(c));
  return d;
#endif
}

// ---------------- LayerNorm (one row of 256 per block) ----------------
template<int TO_BF>
__global__ __launch_bounds__(256) void ln_kernel(const float* __restrict__ x,
    const float* __restrict__ g, const float* __restrict__ b,
    float* __restrict__ outF, unsigned short* __restrict__ outB)
{
  int row = blockIdx.x, c = threadIdx.x;
  float v = x[(size_t)row*C_DIM + c];
  float s1 = v, s2 = v*v;
  #pragma unroll
  for (int off=1; off<64; off<<=1){
    s1 += __shfl_xor(s1, off);
    s2 += __shfl_xor(s2, off);
  }
  __shared__ float r1[4], r2[4];
  int wv = c >> 6;
  if ((c & 63) == 0){ r1[wv] = s1; r2[wv] = s2; }
  __syncthreads();
  s1 = r1[0]+r1[1]+r1[2]+r1[3];
  s2 = r2[0]+r2[1]+r2[2]+r2[3];
  float mu  = s1 * (1.0f/C_DIM);
  float var = s2 * (1.0f/C_DIM) - mu*mu;
  float inv = 1.0f / sqrtf(var + 1e-5f);
  float o = (v - mu) * inv * g[c] + b[c];
  if (TO_BF) outB[(size_t)row*C_DIM + c] = f2bf(o);
  else       outF[(size_t)row*C_DIM + c] = o;
}

// ---------------- 64x64 tiled transpose: src[R][C] -> dst[C][R] ----------------
__global__ __launch_bounds__(256) void transpose_k(const float* __restrict__ src,
    float* __restrict__ dstF, unsigned short* __restrict__ dstB, int R, int Cc)
{
  __shared__ float t[64][65];
  int c0 = blockIdx.x*64, r0 = blockIdx.y*64;
  int x = threadIdx.x & 63, ys = threadIdx.x >> 6;
  #pragma unroll
  for (int i=0;i<16;++i){
    int r = ys + i*4;
    t[r][x] = src[(size_t)(r0+r)*Cc + c0 + x];
  }
  __syncthreads();
  #pragma unroll
  for (int i=0;i<16;++i){
    int rr = ys + i*4;
    float val = t[x][rr];
    if (dstB) dstB[(size_t)(c0+rr)*R + r0 + x] = f2bf(val);
    else      dstF[(size_t)(c0+rr)*R + r0 + x] = val;
  }
}

__global__ void cvt_bf(const float* __restrict__ src, unsigned short* __restrict__ dst, int n){
  int i = blockIdx.x*256 + threadIdx.x;
  if (i < n) dst[i] = f2bf(src[i]);
}

// ---------------- repack K into MFMA-fragment order ----------------
__global__ __launch_bounds__(256) void repack_k(const unsigned short* __restrict__ kbf,
                                               unsigned short* __restrict__ kpack)
{
  int blk = blockIdx.x;          // h*256 + t
  int t = blk & 255, h = blk >> 8;
  int tid = threadIdx.x;
  int lane = tid >> 2;
  int j = (tid & 3) * 2;
  int l16 = lane & 15, lg = lane >> 4;
  unsigned val = *(const unsigned*)(kbf + (size_t)(t*16 + l16)*C_DIM + h*HDIM + lg*8 + j);
  *(unsigned*)(kpack + (size_t)blk*512 + tid*2) = val;
}

// ---------------- 16x32-wave GEMM (2 waves/block), optional split-K partials ----
template<int RELU>
__global__ __launch_bounds__(128) void gemm16x32(
    const unsigned short* __restrict__ A, const unsigned short* __restrict__ Wt,
    const float* __restrict__ bias, const float* __restrict__ resid,
    float* __restrict__ outF, unsigned short* __restrict__ outB,
    int K, int kchunk, float* __restrict__ pbuf)
{
  int wave = threadIdx.x >> 6, lane = threadIdx.x & 63;
  int l16 = lane & 15, lg = lane >> 4;
  int m0 = blockIdx.x*32 + wave*16;
  int n0 = blockIdx.y*32;
  int ks0 = blockIdx.z * kchunk;
  f32x4 acc0={0.f,0.f,0.f,0.f}, acc1=acc0;
  const unsigned short* ap  = A  + (size_t)(m0+l16)*K + ks0 + lg*8;
  const unsigned short* bp0 = Wt + (size_t)(n0   +l16)*K + ks0 + lg*8;
  const unsigned short* bp1 = Wt + (size_t)(n0+16+l16)*K + ks0 + lg*8;
  for (int ks = 0; ks < kchunk; ks += 32){
    i32x4 af = *(const i32x4*)(ap + ks);
    acc0 = mfma16(af, *(const i32x4*)(bp0 + ks), acc0);
    acc1 = mfma16(af, *(const i32x4*)(bp1 + ks), acc1);
  }
  if (pbuf){
    float* pb = pbuf + (size_t)blockIdx.z * (N_TOK*C_DIM);
    #pragma unroll
    for (int f=0; f<2; ++f){
      f32x4 acc = f ? acc1 : acc0;
      int n = n0 + f*16 + l16;
      #pragma unroll
      for (int r=0;r<4;++r)
        pb[(size_t)(m0 + lg*4 + r)*C_DIM + n] = acc[r];
    }
  } else {
    #pragma unroll
    for (int f=0; f<2; ++f){
      f32x4 acc = f ? acc1 : acc0;
      int n = n0 + f*16 + l16;
      float bb = bias[n];
      #pragma unroll
      for (int r=0;r<4;++r){
        int m = m0 + lg*4 + r;
        float val = acc[r] + bb;
        if (RELU) val = fmaxf(val, 0.0f);
        if (resid) val += resid[(size_t)m*C_DIM + n];
        if (outF) outF[(size_t)m*C_DIM + n] = val;
        if (outB) outB[(size_t)m*C_DIM + n] = f2bf(val);
      }
    }
  }
}

// ---------------- fused q/kv/v GEMM: Wt rows 0-255 q, 256-511 k, 512-767 v ----
__global__ __launch_bounds__(128) void gemm_qkv(
    const unsigned short* __restrict__ A, const unsigned short* __restrict__ Wt,
    const float* __restrict__ q_b, const float* __restrict__ kv_b,
    unsigned short* __restrict__ qbf, unsigned short* __restrict__ kbf,
    float* __restrict__ vbuf)
{
  int wave = threadIdx.x >> 6, lane = threadIdx.x & 63;
  int l16 = lane & 15, lg = lane >> 4;
  int m0 = blockIdx.x*32 + wave*16;
  int n0 = blockIdx.y*32;
  f32x4 acc0={0.f,0.f,0.f,0.f}, acc1=acc0;
  const unsigned short* ap  = A  + (size_t)(m0+l16)*C_DIM + lg*8;
  const unsigned short* bp0 = Wt + (size_t)(n0   +l16)*C_DIM + lg*8;
  const unsigned short* bp1 = Wt + (size_t)(n0+16+l16)*C_DIM + lg*8;
  for (int ks = 0; ks < C_DIM; ks += 32){
    i32x4 af = *(const i32x4*)(ap + ks);
    acc0 = mfma16(af, *(const i32x4*)(bp0 + ks), acc0);
    acc1 = mfma16(af, *(const i32x4*)(bp1 + ks), acc1);
  }
  #pragma unroll
  for (int f=0; f<2; ++f){
    f32x4 acc = f ? acc1 : acc0;
    int n = n0 + f*16 + l16;
    float bb = (n < 256) ? q_b[n] : kv_b[n-256];
    #pragma unroll
    for (int r=0;r<4;++r){
      int m = m0 + lg*4 + r;
      float val = acc[r] + bb;
      if (n < 256)      qbf[(size_t)m*C_DIM + n]        = f2bf(fmaxf(val, 0.f));
      else if (n < 512) kbf[(size_t)m*C_DIM + (n-256)]  = f2bf(val);
      else              vbuf[(size_t)m*C_DIM + (n-512)] = val;
    }
  }
}

// ---------------- split-K reduce: out = p0 + p1 + bias + resid ----------------
__global__ __launch_bounds__(256) void reduce_conv1(const float* __restrict__ pbuf,
    const float* __restrict__ bias, const float* __restrict__ resid,
    float* __restrict__ out)
{
  int i = (blockIdx.x*256 + threadIdx.x) * 4;
  f32x4 a = *(const f32x4*)(pbuf + i);
  f32x4 b = *(const f32x4*)(pbuf + (size_t)N_TOK*C_DIM + i);
  f32x4 r = *(const f32x4*)(resid + i);
  f32x4 bb = *(const f32x4*)(bias + (i & 255));
  *(f32x4*)(out + i) = a + b + r + bb;
}

// ---------------- column sum of v (for closed-form softmax) ----------------
__global__ __launch_bounds__(256) void colsum_part(const float* __restrict__ v, float* __restrict__ part){
  int b = blockIdx.x, c = threadIdx.x;
  float s = 0.f;
  for (int r=0;r<64;++r) s += v[(size_t)(b*64+r)*C_DIM + c];
  part[b*C_DIM + c] = s;
}
__global__ __launch_bounds__(256) void colsum_final(const float* __restrict__ part, float* __restrict__ sumv){
  int c = threadIdx.x;
  float s = 0.f;
  for (int b=0;b<64;++b) s += part[b*C_DIM + c];
  sumv[c] = s;
}

// ------- bitonic top-8 merge of sorted lists across xor-lane partners -------
#define CMPEX(A,I,i,j) { bool sw = (A[j] > A[i]) || (A[j]==A[i] && I[j]<I[i]); \
  float fv_ = sw?A[j]:A[i]; float sv_ = sw?A[i]:A[j]; \
  int fi_ = sw?I[j]:I[i]; int si_ = sw?I[i]:I[j]; \
  A[i]=fv_; A[j]=sv_; I[i]=fi_; I[j]=si_; }

template<int MLO, int MHI>
__device__ __forceinline__ void merge_lists(float (&tv)[8], int (&ti)[8]){
  #pragma unroll
  for (int m=MLO; m<=MHI; m<<=1){
    float ov[8]; int oi[8];
    #pragma unroll
    for (int j=0;j<8;++j){ ov[j] = __shfl_xor(tv[j], m); oi[j] = __shfl_xor(ti[j], m); }
    #pragma unroll
    for (int j=0;j<8;++j){
      float bv = ov[7-j]; int bi = oi[7-j];
      bool take = (bv > tv[j]) || (bv == tv[j] && bi < ti[j]);
      tv[j] = take?bv:tv[j]; ti[j] = take?bi:ti[j];
    }
    CMPEX(tv,ti,0,4) CMPEX(tv,ti,1,5) CMPEX(tv,ti,2,6) CMPEX(tv,ti,3,7)
    CMPEX(tv,ti,0,2) CMPEX(tv,ti,1,3) CMPEX(tv,ti,4,6) CMPEX(tv,ti,5,7)
    CMPEX(tv,ti,0,1) CMPEX(tv,ti,2,3) CMPEX(tv,ti,4,5) CMPEX(tv,ti,6,7)
  }
}

// block = 16 q-rows x 4 waves; wave w scans packed K-tiles [w*64, w*64+64) sequentially.
// Phase 1: lane-local 4-tile group maxes (16 cols), per-lane top-8, lane-group +
//          cross-wave merges. Phase 2: exact rescan of 8 groups (128 cols/row;
//          16 thr/row x 8 cols, v_dot2_bf16). Phase 3: closed-form softmax + PV.
__global__ __launch_bounds__(256, 4) void attn_kernel(
    const unsigned short* __restrict__ qbf, const unsigned short* __restrict__ kbf,
    const unsigned short* __restrict__ kpack,
    const float* __restrict__ v, const float* __restrict__ sumv,
    unsigned short* __restrict__ outbf)
{
  const int head = blockIdx.y;
  const int tid  = threadIdx.x;
  const int wave = tid >> 6, lane = tid & 63;
  const int l16 = lane & 15, lg = lane >> 4;
  const int row0 = blockIdx.x * 16;

  __shared__ float ls_v[4][16][8];
  __shared__ int   ls_i[4][16][8];
  __shared__ int   gsel[16][8];
  __shared__ float lds_e[16][8];
  __shared__ int   lds_idx[16][8];
  __shared__ float lds_d[16];

  // ---- phase 1: sequential packed-K MFMA scan, 4-tile group maxes ----
  i32x4 qf = *(const i32x4*)(qbf + (size_t)(row0 + l16)*C_DIM + head*HDIM + lg*8);
  const f32x4 zacc = {0.f,0.f,0.f,0.f};
  const int tbase = wave * 64;
  const unsigned short* kp = kpack + ((size_t)(head*256 + tbase)*64 + lane)*8;

  float tv[8]; int ti[8];
  #pragma unroll
  for (int j=0;j<8;++j){ tv[j]=-3e38f; ti[j]=0x7fffffff; }

  i32x4 kr0 = *(const i32x4*)(kp);
  i32x4 kr1 = *(const i32x4*)(kp + 512);
  i32x4 kr2 = *(const i32x4*)(kp + 1024);
  i32x4 kr3 = *(const i32x4*)(kp + 1536);
  for (int g = 0; g < 16; ++g){
    float gm = -3e38f;
    #pragma unroll
    for (int u = 0; u < 4; ++u){
      int t = g*4 + u;
      i32x4 cur = (u==0)?kr0 : (u==1)?kr1 : (u==2)?kr2 : kr3;
      f32x4 a0 = mfma16(cur, qf, zacc);
      i32x4 nxt = *(const i32x4*)(kp + (size_t)(t+4)*512);  // over-read (<=4KB) lands in qbf: safe
      if (u==0) kr0=nxt; else if (u==1) kr1=nxt; else if (u==2) kr2=nxt; else kr3=nxt;
      gm = fmaxf(gm, fmaxf(fmaxf(a0[0],a0[1]), fmaxf(a0[2],a0[3])));
    }
    if (gm > tv[7]){
      float cv = gm; int ci = (tbase + g*4)*16 + lg*4;   // group id = min col
      #pragma unroll
      for (int j=0;j<8;++j){
        bool gt = cv > tv[j];            // strict: ascending stream keeps earliest on tie
        float nv = gt?cv:tv[j]; float ov_ = gt?tv[j]:cv;
        int   ni = gt?ci:ti[j]; int   oi_ = gt?ti[j]:ci;
        tv[j]=nv; ti[j]=ni; cv=ov_; ci=oi_;
      }
    }
  }
  merge_lists<16,32>(tv, ti);   // per-row top-8 groups of this wave's chunk

  if (lg == 0){
    #pragma unroll
    for (int j=0;j<8;++j){ ls_v[wave][l16][j]=tv[j]; ls_i[wave][l16][j]=ti[j]; }
  }
  __syncthreads();

  if (wave == 0){
    float mv[8]; int mi[8];
    #pragma unroll
    for (int j=0;j<8;++j){ mv[j]=ls_v[lg][l16][j]; mi[j]=ls_i[lg][l16][j]; }
    merge_lists<16,32>(mv, mi);   // global top-8 groups per row
    if (lg == 0){
      #pragma unroll
      for (int j=0;j<8;++j) gsel[l16][j] = mi[j];
    }
  }
  __syncthreads();

  // ---- phase 2: exact rescan; 16 threads/row, 8 cols each (half a group) ----
  const int prow = tid >> 4;              // 0..15
  const int sub  = tid & 15;              // 0..15
  unsigned q2u[16];
  {
    const unsigned short* qrow = qbf + (size_t)(row0 + prow)*C_DIM + head*HDIM;
    #pragma unroll
    for (int i=0;i<4;++i){
      i32x4 qv = *(const i32x4*)(qrow + i*8);
      #pragma unroll
      for (int j=0;j<4;++j) q2u[i*4+j] = (unsigned)qv[j];
    }
  }
  int c0 = gsel[prow][sub >> 1];
  int ibase = (sub & 1) * 2;
  float sv[8]; int si[8];
  #pragma unroll
  for (int j=0;j<8;++j){ sv[j] = -3e38f; si[j] = 0x7fffffff; }
  #pragma unroll
  for (int ii=0; ii<2; ++ii){             // 2 tiles of the half-group
    #pragma unroll
    for (int rr=0; rr<4; ++rr){           // 4 cols per tile
      int col = c0 + 16*(ibase+ii) + rr;
      const unsigned short* krow = kbf + (size_t)col*C_DIM + head*HDIM;
      float s = 0.f;
      #pragma unroll
      for (int q=0;q<4;++q){
        i32x4 kv = *(const i32x4*)(krow + q*8);
        #pragma unroll
        for (int j=0;j<4;++j) s = dot2bf((unsigned)kv[j], q2u[q*4+j], s);
      }
      float cv = s; int ci = col;         // 8 candidates for top-8: insert unconditionally
      #pragma unroll
      for (int j=0;j<8;++j){
        bool gt = (cv > sv[j]) || (cv == sv[j] && ci < si[j]);
        float nv = gt?cv:sv[j]; float ov_ = gt?sv[j]:cv;
        int   ni = gt?ci:si[j]; int   oi_ = gt?si[j]:ci;
        sv[j]=nv; si[j]=ni; cv=ov_; ci=oi_;
      }
    }
  }
  merge_lists<1,8>(sv, si);               // exact top-8 elements per row

  if (sub == 0){
    float den = 4096.0f;
    #pragma unroll
    for (int j=0;j<8;++j){
      float e = expm1f(sv[j]*SCALE);
      den += e;
      lds_e[prow][j] = e;
      lds_idx[prow][j] = si[j];
    }
    lds_d[prow] = den;
  }
  __syncthreads();

  // ---- phase 3: closed-form masked softmax PV: 16 rows x 32 dims ----
  #pragma unroll
  for (int it=0; it<2; ++it){
    int flat = it*256 + tid;
    int rl = flat >> 5, d = flat & 31;
    float num = sumv[head*HDIM + d];
    float den = lds_d[rl];
    #pragma unroll
    for (int j=0;j<8;++j)
      num += lds_e[rl][j] * v[(size_t)lds_idx[rl][j]*C_DIM + head*HDIM + d];
    outbf[(size_t)(row0 + rl)*C_DIM + head*HDIM + d] = f2bf(num/den);
  }
}

// ---------------- LDS-tiled grouped dwconv 3x3 & 5x5 -> cat[p][2048] bf16 ----------------
__global__ __launch_bounds__(256) void dwconv_tiled(const float* __restrict__ img, // h2T [256][4096]
    const float* __restrict__ w3, const float* __restrict__ b3,
    const float* __restrict__ w5, const float* __restrict__ b5,
    unsigned short* __restrict__ cat)
{
  __shared__ float tile[8][513];
  int ic0 = blockIdx.x * 8;
  int py0 = blockIdx.y * 4;
  int tid = threadIdx.x;

  #pragma unroll
  for (int i = 0; i < 16; ++i){
    int idx = i*256 + tid;
    int ch  = idx >> 9;
    int rem = idx & 511;
    int ry  = rem >> 6, x = rem & 63;
    int y   = py0 - 2 + ry;
    float v = (y >= 0 && y < 64) ? img[(size_t)(ic0+ch)*4096 + y*64 + x] : 0.f;
    tile[ch][ry*64 + x] = v;
  }
  __syncthreads();

  int o_l  = tid & 31;
  int p_l  = tid >> 5;
  int ic_l = o_l >> 2;
  int o3   = ic0*4 + o_l;
  const float* pl = tile[ic_l];

  float W3[9], W5[25];
  #pragma unroll
  for (int i=0;i<9;++i)  W3[i] = w3[o3*9+i];
  #pragma unroll
  for (int i=0;i<25;++i) W5[i] = w5[o3*25+i];
  float bb3 = b3[o3], bb5 = b5[o3];

  #pragma unroll 4
  for (int it = 0; it < 32; ++it){
    int pp = it*8 + p_l;
    int ly = (pp >> 6) + 2;
    int x  = pp & 63;
    float a3 = bb3, a5 = bb5;
    #pragma unroll
    for (int dy=-2; dy<=2; ++dy){
      #pragma unroll
      for (int dx=-2; dx<=2; ++dx){
        int xx = x + dx;
        float iv = (xx >= 0 && xx < 64) ? pl[(ly+dy)*64 + xx] : 0.f;
        a5 += W5[(dy+2)*5 + dx+2] * iv;
        if (dy>=-1 && dy<=1 && dx>=-1 && dx<=1)
          a3 += W3[(dy+1)*3 + dx+1] * iv;
      }
    }
    int p = (py0 + (pp>>6))*64 + x;
    cat[(size_t)p*2048 + o3]        = f2bf(fmaxf(a3, 0.f));
    cat[(size_t)p*2048 + 1024 + o3] = f2bf(fmaxf(a5, 0.f));
  }
}

extern "C" void kernel_launch(void* const* d_in, const int* in_sizes, int n_in,
                              void* d_out, int out_size, void* d_ws, size_t ws_size,
                              hipStream_t stream)
{
  (void)in_sizes; (void)n_in; (void)out_size; (void)ws_size;
  const float* x      = (const float*)d_in[0];
  const float* ln1_g  = (const float*)d_in[3];
  const float* ln1_b  = (const float*)d_in[4];
  const float* q_w    = (const float*)d_in[5];
  const float* q_b    = (const float*)d_in[6];
  const float* kv_w   = (const float*)d_in[7];
  const float* kv_b   = (const float*)d_in[8];
  const float* proj_w = (const float*)d_in[9];
  const float* proj_b = (const float*)d_in[10];
  const float* ln2_g  = (const float*)d_in[11];
  const float* ln2_b  = (const float*)d_in[12];
  const float* w3     = (const float*)d_in[13];
  const float* b3     = (const float*)d_in[14];
  const float* w5     = (const float*)d_in[15];
  const float* b5     = (const float*)d_in[16];
  const float* w1     = (const float*)d_in[17];
  const float* b1     = (const float*)d_in[18];
  float* out = (float*)d_out;
  char* ws = (char*)d_ws;

  unsigned short* wAll = (unsigned short*)(ws + 0x0);       // 384 KB: q(256)|k,v(512) rows x 256
  unsigned short* pwT  = (unsigned short*)(ws + 0x60000);   // 128 KB
  unsigned short* w1bf = (unsigned short*)(ws + 0x80000);   // 1 MB
  unsigned short* hbf  = (unsigned short*)(ws + 0x180000);  // 2 MB
  unsigned short* qbf  = (unsigned short*)(ws + 0x380000);  // 2 MB
  unsigned short* kbf  = (unsigned short*)(ws + 0x580000);  // 2 MB
  float*          vbuf = (float*)(ws + 0x780000);           // 4 MB
  unsigned short* obf  = (unsigned short*)(ws + 0xB80000);  // 2 MB
  float*          x2   = (float*)(ws + 0xD80000);           // 4 MB
  float*          sumv = (float*)(ws + 0x1180000);          // 1 KB
  float*          part = (float*)(ws + 0x1190000);          // 64 KB
  unsigned short* kpack= (unsigned short*)(ws + 0x180000);  // 2 MB, reuse hbf (dead after qkv)
  float*          h2   = (float*)(ws + 0x180000);           // 4 MB, reuse hbf+qbf after attn
  float*          h2T  = (float*)(ws + 0x580000);           // 4 MB, reuse kbf+vbuf-lo after attn
  float*          pbuf = (float*)(ws + 0x180000);           // 8 MB, reuse h2/h2T after dwconv
  unsigned short* cat  = (unsigned short*)(ws + 0x1200000); // 16 MB -> end 0x2200000

  dim3 b256(256), b128(128);

  // weight prep
  cvt_bf<<<dim3(2048), b256, 0, stream>>>(w1, w1bf, 256*2048);
  transpose_k<<<dim3(4,4), b256, 0, stream>>>(q_w,   nullptr, wAll,  256, 256);
  transpose_k<<<dim3(8,4), b256, 0, stream>>>(kv_w,  nullptr, wAll + 256*256, 256, 512);
  transpose_k<<<dim3(4,4), b256, 0, stream>>>(proj_w,nullptr, pwT,  256, 256);

  // attention branch
  ln_kernel<1><<<dim3(4096), b256, 0, stream>>>(x, ln1_g, ln1_b, nullptr, hbf);
  gemm_qkv<<<dim3(128,24), b128, 0, stream>>>(hbf, wAll, q_b, kv_b, qbf, kbf, vbuf);
  repack_k<<<dim3(2048), b256, 0, stream>>>(kbf, kpack);    // overwrites hbf region (now dead)
  colsum_part <<<dim3(64), b256, 0, stream>>>(vbuf, part);
  colsum_final<<<dim3(1),  b256, 0, stream>>>(part, sumv);
  attn_kernel<<<dim3(256,8), b256, 0, stream>>>(qbf, kbf, kpack, vbuf, sumv, obf);
  gemm16x32<0><<<dim3(128,8,1), b128, 0, stream>>>(obf, pwT, proj_b, x, x2, nullptr, 256, 256, nullptr);

  // MSFN branch
  ln_kernel<0><<<dim3(4096), b256, 0, stream>>>(x2, ln2_g, ln2_b, h2, nullptr);
  transpose_k<<<dim3(4,64), b256, 0, stream>>>(h2, h2T, nullptr, 4096, 256);
  dwconv_tiled<<<dim3(32,16), b256, 0, stream>>>(h2T, w3, b3, w5, b5, cat);
  gemm16x32<0><<<dim3(128,8,2), b128, 0, stream>>>(cat, w1bf, nullptr, nullptr, nullptr, nullptr, 2048, 1024, pbuf);
  reduce_conv1<<<dim3(1024), b256, 0, stream>>>(pbuf, b1, x2, out);
}

// Round 11
// 194.758 us; speedup vs baseline: 1.0881x; 1.0603x over previous
//
#include <hip/hip_runtime.h>
#include <math.h>

#define N_TOK 4096
#define C_DIM 256
#define HEADS 8
#define HDIM  32
#define SCALE 0.17677669529663687f

typedef float f32x4 __attribute__((ext_vector_type(4)));
typedef float f32x2 __attribute__((ext_vector_type(2)));
typedef int   i32x4 __attribute__((ext_vector_type(4)));
typedef __bf16 bf16x8 __attribute__((ext_vector_type(8)));

#if defined(__has_builtin)
#if __has_builtin(__builtin_amdgcn_mfma_f32_16x16x32_bf16)
#define HAVE_MFMA_BUILTIN 1
#endif
#endif

__device__ __forceinline__ unsigned short f2bf(float x){
  unsigned u = __float_as_uint(x);
  u += 0x7FFFu + ((u >> 16) & 1u);
  return (unsigned short)(u >> 16);
}

// order-preserving float->uint (monotone: s1 > s2  <=>  key(s1) > key(s2))
__device__ __forceinline__ unsigned f2key(float s){
  unsigned b = __float_as_uint(s);
  return b ^ ((unsigned)((int)b >> 31) | 0x80000000u);
}
__device__ __forceinline__ unsigned umax_(unsigned a, unsigned b){ return a > b ? a : b; }
__device__ __forceinline__ unsigned umin_(unsigned a, unsigned b){ return a < b ? a : b; }

// comparator: max to lower index (descending order), 2 VALU (v_max_u32/v_min_u32)
#define KCMP(A,i,j) { unsigned h_ = umax_(A[i],A[j]); unsigned l_ = umin_(A[i],A[j]); A[i]=h_; A[j]=l_; }

// Batcher odd-even mergesort, 8 keys, descending. 19 comparators.
__device__ __forceinline__ void sort8(unsigned (&k)[8]){
  KCMP(k,0,1) KCMP(k,2,3) KCMP(k,4,5) KCMP(k,6,7)
  KCMP(k,0,2) KCMP(k,1,3) KCMP(k,4,6) KCMP(k,5,7)
  KCMP(k,1,2) KCMP(k,5,6)
  KCMP(k,0,4) KCMP(k,1,5) KCMP(k,2,6) KCMP(k,3,7)
  KCMP(k,2,4) KCMP(k,3,5)
  KCMP(k,1,2) KCMP(k,3,4) KCMP(k,5,6)
}

// top-8 of 16 keys: sort both halves desc, bitonic top-8 merge. Result in t (sorted desc).
__device__ __forceinline__ void top8of16(unsigned (&g)[16], unsigned (&t)[8]){
  unsigned a[8], b[8];
  #pragma unroll
  for (int j=0;j<8;++j){ a[j]=g[j]; b[j]=g[8+j]; }
  sort8(a); sort8(b);
  #pragma unroll
  for (int j=0;j<8;++j) t[j] = umax_(a[j], b[7-j]);
  KCMP(t,0,4) KCMP(t,1,5) KCMP(t,2,6) KCMP(t,3,7)
  KCMP(t,0,2) KCMP(t,1,3) KCMP(t,4,6) KCMP(t,5,7)
  KCMP(t,0,1) KCMP(t,2,3) KCMP(t,4,5) KCMP(t,6,7)
}

// merge sorted-8 lists across xor-lane partners; all lanes end with the top-8 (sorted).
template<int MLO, int MHI>
__device__ __forceinline__ void merge_keys(unsigned (&k)[8]){
  #pragma unroll
  for (int m=MLO; m<=MHI; m<<=1){
    unsigned o[8];
    #pragma unroll
    for (int j=0;j<8;++j) o[j] = (unsigned)__shfl_xor((int)k[j], m);
    #pragma unroll
    for (int j=0;j<8;++j) k[j] = umax_(k[j], o[7-j]);
    KCMP(k,0,4) KCMP(k,1,5) KCMP(k,2,6) KCMP(k,3,7)
    KCMP(k,0,2) KCMP(k,1,3) KCMP(k,4,6) KCMP(k,5,7)
    KCMP(k,0,1) KCMP(k,2,3) KCMP(k,4,5) KCMP(k,6,7)
  }
}

// D = A(16x32) * B(32x16) + C via v_mfma_f32_16x16x32_bf16.
__device__ __forceinline__ f32x4 mfma16(i32x4 a, i32x4 b, f32x4 c){
#ifdef HAVE_MFMA_BUILTIN
  return __builtin_amdgcn_mfma_f32_16x16x32_bf16(
      __builtin_bit_cast(bf16x8, a), __builtin_bit_cast(bf16x8, b), c, 0, 0, 0);
#else
  f32x4 d;
  asm volatile("v_mfma_f32_16x16x32_bf16 %0, %1, %2, %3\n\ts_nop 7\n\ts_nop 3"
               : "=&v"(d) : "v"(a), "v"(b), "v"(c));
  return d;
#endif
}

// ---------------- LayerNorm (one row of 256 per block) ----------------
template<int TO_BF>
__global__ __launch_bounds__(256) void ln_kernel(const float* __restrict__ x,
    const float* __restrict__ g, const float* __restrict__ b,
    float* __restrict__ outF, unsigned short* __restrict__ outB)
{
  int row = blockIdx.x, c = threadIdx.x;
  float v = x[(size_t)row*C_DIM + c];
  float s1 = v, s2 = v*v;
  #pragma unroll
  for (int off=1; off<64; off<<=1){
    s1 += __shfl_xor(s1, off);
    s2 += __shfl_xor(s2, off);
  }
  __shared__ float r1[4], r2[4];
  int wv = c >> 6;
  if ((c & 63) == 0){ r1[wv] = s1; r2[wv] = s2; }
  __syncthreads();
  s1 = r1[0]+r1[1]+r1[2]+r1[3];
  s2 = r2[0]+r2[1]+r2[2]+r2[3];
  float mu  = s1 * (1.0f/C_DIM);
  float var = s2 * (1.0f/C_DIM) - mu*mu;
  float inv = 1.0f / sqrtf(var + 1e-5f);
  float o = (v - mu) * inv * g[c] + b[c];
  if (TO_BF) outB[(size_t)row*C_DIM + c] = f2bf(o);
  else       outF[(size_t)row*C_DIM + c] = o;
}

// ---------------- 64x64 tiled transpose: src[R][C] -> dst[C][R] ----------------
__global__ __launch_bounds__(256) void transpose_k(const float* __restrict__ src,
    float* __restrict__ dstF, unsigned short* __restrict__ dstB, int R, int Cc)
{
  __shared__ float t[64][65];
  int c0 = blockIdx.x*64, r0 = blockIdx.y*64;
  int x = threadIdx.x & 63, ys = threadIdx.x >> 6;
  #pragma unroll
  for (int i=0;i<16;++i){
    int r = ys + i*4;
    t[r][x] = src[(size_t)(r0+r)*Cc + c0 + x];
  }
  __syncthreads();
  #pragma unroll
  for (int i=0;i<16;++i){
    int rr = ys + i*4;
    float val = t[x][rr];
    if (dstB) dstB[(size_t)(c0+rr)*R + r0 + x] = f2bf(val);
    else      dstF[(size_t)(c0+rr)*R + r0 + x] = val;
  }
}

__global__ void cvt_bf(const float* __restrict__ src, unsigned short* __restrict__ dst, int n){
  int i = blockIdx.x*256 + threadIdx.x;
  if (i < n) dst[i] = f2bf(src[i]);
}

// ---------------- repack K into MFMA-fragment order ----------------
__global__ __launch_bounds__(256) void repack_k(const unsigned short* __restrict__ kbf,
                                               unsigned short* __restrict__ kpack)
{
  int blk = blockIdx.x;          // h*256 + t
  int t = blk & 255, h = blk >> 8;
  int tid = threadIdx.x;
  int lane = tid >> 2;
  int j = (tid & 3) * 2;
  int l16 = lane & 15, lg = lane >> 4;
  unsigned val = *(const unsigned*)(kbf + (size_t)(t*16 + l16)*C_DIM + h*HDIM + lg*8 + j);
  *(unsigned*)(kpack + (size_t)blk*512 + tid*2) = val;
}

// ---------------- 16x32-wave GEMM (2 waves/block), optional split-K partials ----
template<int RELU>
__global__ __launch_bounds__(128) void gemm16x32(
    const unsigned short* __restrict__ A, const unsigned short* __restrict__ Wt,
    const float* __restrict__ bias, const float* __restrict__ resid,
    float* __restrict__ outF, unsigned short* __restrict__ outB,
    int K, int kchunk, float* __restrict__ pbuf)
{
  int wave = threadIdx.x >> 6, lane = threadIdx.x & 63;
  int l16 = lane & 15, lg = lane >> 4;
  int m0 = blockIdx.x*32 + wave*16;
  int n0 = blockIdx.y*32;
  int ks0 = blockIdx.z * kchunk;
  f32x4 acc0={0.f,0.f,0.f,0.f}, acc1=acc0;
  const unsigned short* ap  = A  + (size_t)(m0+l16)*K + ks0 + lg*8;
  const unsigned short* bp0 = Wt + (size_t)(n0   +l16)*K + ks0 + lg*8;
  const unsigned short* bp1 = Wt + (size_t)(n0+16+l16)*K + ks0 + lg*8;
  for (int ks = 0; ks < kchunk; ks += 32){
    i32x4 af = *(const i32x4*)(ap + ks);
    acc0 = mfma16(af, *(const i32x4*)(bp0 + ks), acc0);
    acc1 = mfma16(af, *(const i32x4*)(bp1 + ks), acc1);
  }
  if (pbuf){
    float* pb = pbuf + (size_t)blockIdx.z * (N_TOK*C_DIM);
    #pragma unroll
    for (int f=0; f<2; ++f){
      f32x4 acc = f ? acc1 : acc0;
      int n = n0 + f*16 + l16;
      #pragma unroll
      for (int r=0;r<4;++r)
        pb[(size_t)(m0 + lg*4 + r)*C_DIM + n] = acc[r];
    }
  } else {
    #pragma unroll
    for (int f=0; f<2; ++f){
      f32x4 acc = f ? acc1 : acc0;
      int n = n0 + f*16 + l16;
      float bb = bias[n];
      #pragma unroll
      for (int r=0;r<4;++r){
        int m = m0 + lg*4 + r;
        float val = acc[r] + bb;
        if (RELU) val = fmaxf(val, 0.0f);
        if (resid) val += resid[(size_t)m*C_DIM + n];
        if (outF) outF[(size_t)m*C_DIM + n] = val;
        if (outB) outB[(size_t)m*C_DIM + n] = f2bf(val);
      }
    }
  }
}

// ---------------- fused q/kv/v GEMM: Wt rows 0-255 q, 256-511 k, 512-767 v ----
__global__ __launch_bounds__(128) void gemm_qkv(
    const unsigned short* __restrict__ A, const unsigned short* __restrict__ Wt,
    const float* __restrict__ q_b, const float* __restrict__ kv_b,
    unsigned short* __restrict__ qbf, unsigned short* __restrict__ kbf,
    float* __restrict__ vbuf)
{
  int wave = threadIdx.x >> 6, lane = threadIdx.x & 63;
  int l16 = lane & 15, lg = lane >> 4;
  int m0 = blockIdx.x*32 + wave*16;
  int n0 = blockIdx.y*32;
  f32x4 acc0={0.f,0.f,0.f,0.f}, acc1=acc0;
  const unsigned short* ap  = A  + (size_t)(m0+l16)*C_DIM + lg*8;
  const unsigned short* bp0 = Wt + (size_t)(n0   +l16)*C_DIM + lg*8;
  const unsigned short* bp1 = Wt + (size_t)(n0+16+l16)*C_DIM + lg*8;
  for (int ks = 0; ks < C_DIM; ks += 32){
    i32x4 af = *(const i32x4*)(ap + ks);
    acc0 = mfma16(af, *(const i32x4*)(bp0 + ks), acc0);
    acc1 = mfma16(af, *(const i32x4*)(bp1 + ks), acc1);
  }
  #pragma unroll
  for (int f=0; f<2; ++f){
    f32x4 acc = f ? acc1 : acc0;
    int n = n0 + f*16 + l16;
    float bb = (n < 256) ? q_b[n] : kv_b[n-256];
    #pragma unroll
    for (int r=0;r<4;++r){
      int m = m0 + lg*4 + r;
      float val = acc[r] + bb;
      if (n < 256)      qbf[(size_t)m*C_DIM + n]        = f2bf(fmaxf(val, 0.f));
      else if (n < 512) kbf[(size_t)m*C_DIM + (n-256)]  = f2bf(val);
      else              vbuf[(size_t)m*C_DIM + (n-512)] = val;
    }
  }
}

// ---------------- split-K reduce: out = p0 + p1 + bias + resid ----------------
__global__ __launch_bounds__(256) void reduce_conv1(const float* __restrict__ pbuf,
    const float* __restrict__ bias, const float* __restrict__ resid,
    float* __restrict__ out)
{
  int i = (blockIdx.x*256 + threadIdx.x) * 4;
  f32x4 a = *(const f32x4*)(pbuf + i);
  f32x4 b = *(const f32x4*)(pbuf + (size_t)N_TOK*C_DIM + i);
  f32x4 r = *(const f32x4*)(resid + i);
  f32x4 bb = *(const f32x4*)(bias + (i & 255));
  *(f32x4*)(out + i) = a + b + r + bb;
}

// ---------------- column sum of v (for closed-form softmax) ----------------
__global__ __launch_bounds__(256) void colsum_part(const float* __restrict__ v, float* __restrict__ part){
  int b = blockIdx.x, c = threadIdx.x;
  float s = 0.f;
  for (int r=0;r<64;++r) s += v[(size_t)(b*64+r)*C_DIM + c];
  part[b*C_DIM + c] = s;
}
__global__ __launch_bounds__(256) void colsum_final(const float* __restrict__ part, float* __restrict__ sumv){
  int c = threadIdx.x;
  float s = 0.f;
  for (int b=0;b<64;++b) s += part[b*C_DIM + c];
  sumv[c] = s;
}

// block = 32 q-rows x 4 waves; wave w scans packed K-tiles [w*64, w*64+64) sequentially,
// with 2 q-fragments (rows 0-15, 16-31). Selection on packed sort keys:
// phase-1 key = (score_ordered_bits & ~0x3FF) | (1023 - groupcol/4)  (group = 16 cols)
// phase-2 key = (score_ordered_bits & ~0xFFF) | (4095 - col)
__global__ __launch_bounds__(256, 4) void attn_kernel(
    const unsigned short* __restrict__ qbf, const unsigned short* __restrict__ kbf,
    const unsigned short* __restrict__ kpack,
    const float* __restrict__ v, const float* __restrict__ sumv,
    unsigned short* __restrict__ outbf)
{
  const int head = blockIdx.y;
  const int tid  = threadIdx.x;
  const int wave = tid >> 6, lane = tid & 63;
  const int l16 = lane & 15, lg = lane >> 4;
  const int row0 = blockIdx.x * 32;

  __shared__ unsigned ls[4][2][16][8];
  __shared__ int   gsel[32][8];
  __shared__ float lds_e[32][8];
  __shared__ int   lds_idx[32][8];

  // ---- phase 1: sequential packed-K MFMA scan, 4-tile (16-col) group-max keys ----
  i32x4 qf0 = *(const i32x4*)(qbf + (size_t)(row0      + l16)*C_DIM + head*HDIM + lg*8);
  i32x4 qf1 = *(const i32x4*)(qbf + (size_t)(row0 + 16 + l16)*C_DIM + head*HDIM + lg*8);
  const f32x4 zacc = {0.f,0.f,0.f,0.f};
  const int tbase = wave * 64;
  const unsigned short* kp = kpack + ((size_t)(head*256 + tbase)*64 + lane)*8;

  unsigned g0[16], g1[16];
  i32x4 kr0 = *(const i32x4*)(kp);
  i32x4 kr1 = *(const i32x4*)(kp + 512);
  i32x4 kr2 = *(const i32x4*)(kp + 1024);
  i32x4 kr3 = *(const i32x4*)(kp + 1536);
  const int gidbase = 1023 - (tbase*4 + lg);   // group id code base (smaller col -> larger code)
  #pragma unroll
  for (int g = 0; g < 16; ++g){
    float m0 = -3e38f, m1 = -3e38f;
    #pragma unroll
    for (int u = 0; u < 4; ++u){
      int t = g*4 + u;
      i32x4 cur = (u==0)?kr0 : (u==1)?kr1 : (u==2)?kr2 : kr3;
      f32x4 a0 = mfma16(cur, qf0, zacc);
      f32x4 a1 = mfma16(cur, qf1, zacc);
      i32x4 nxt = *(const i32x4*)(kp + (size_t)(t+4)*512);  // over-read (<=4KB) lands in qbf: safe
      if (u==0) kr0=nxt; else if (u==1) kr1=nxt; else if (u==2) kr2=nxt; else kr3=nxt;
      m0 = fmaxf(m0, fmaxf(fmaxf(a0[0],a0[1]), fmaxf(a0[2],a0[3])));
      m1 = fmaxf(m1, fmaxf(fmaxf(a1[0],a1[1]), fmaxf(a1[2],a1[3])));
    }
    unsigned code = (unsigned)(gidbase - g*16);
    g0[g] = (f2key(m0) & 0xFFFFFC00u) | code;
    g1[g] = (f2key(m1) & 0xFFFFFC00u) | code;
  }
  unsigned t0[8], t1[8];
  top8of16(g0, t0);
  top8of16(g1, t1);
  merge_keys<16,32>(t0);      // row's top-8 groups of this wave's chunk
  merge_keys<16,32>(t1);

  if (lg == 0){
    #pragma unroll
    for (int j=0;j<8;++j){ ls[wave][0][l16][j]=t0[j]; ls[wave][1][l16][j]=t1[j]; }
  }
  __syncthreads();

  if (wave < 2){
    unsigned mk[8];
    #pragma unroll
    for (int j=0;j<8;++j) mk[j] = ls[lg][wave][l16][j];
    merge_keys<16,32>(mk);    // global top-8 groups per row
    if (lg == 0){
      #pragma unroll
      for (int j=0;j<8;++j) gsel[wave*16 + l16][j] = (1023 - (int)(mk[j] & 1023u)) << 2;
    }
  }
  __syncthreads();

  // ---- phase 2: exact rescan; 8 threads/row, one group (16 cols) each ----
  const int prow = tid >> 3;              // 0..31
  const int sub  = tid & 7;               // 0..7
  f32x2 q2[16];
  {
    const unsigned short* qrow = qbf + (size_t)(row0 + prow)*C_DIM + head*HDIM;
    #pragma unroll
    for (int i=0;i<4;++i){
      i32x4 qv = *(const i32x4*)(qrow + i*8);
      #pragma unroll
      for (int j=0;j<4;++j){
        unsigned u = (unsigned)qv[j];
        f32x2 p; p.x = __uint_as_float(u << 16); p.y = __uint_as_float(u & 0xFFFF0000u);
        q2[i*4+j] = p;
      }
    }
  }
  int base = gsel[prow][sub];
  unsigned sv[8];
  #pragma unroll
  for (int j=0;j<8;++j) sv[j] = 0u;
  #pragma unroll
  for (int t=0;t<4;++t){
    #pragma unroll
    for (int r=0;r<4;++r){
      int col = base + 16*t + r;
      const unsigned short* krow = kbf + (size_t)col*C_DIM + head*HDIM;
      f32x2 acc = {0.f, 0.f};
      #pragma unroll
      for (int q=0;q<4;++q){
        i32x4 kv = *(const i32x4*)(krow + q*8);
        #pragma unroll
        for (int j=0;j<4;++j){
          unsigned u = (unsigned)kv[j];
          f32x2 p; p.x = __uint_as_float(u << 16); p.y = __uint_as_float(u & 0xFFFF0000u);
          acc += p * q2[q*4+j];
        }
      }
      float s = acc.x + acc.y;
      unsigned kk = (f2key(s) & 0xFFFFF000u) | (unsigned)(4095 - col);
      #pragma unroll
      for (int j=0;j<8;++j){ unsigned h = umax_(sv[j], kk); kk = umin_(sv[j], kk); sv[j] = h; }
    }
  }
  merge_keys<1,4>(sv);        // top-8 elements per row (all 8 subs identical)

  // recompute exact f32 score for this thread's selected element, stash e/idx
  {
    int col = 4095 - (int)(sv[sub] & 4095u);
    const unsigned short* krow = kbf + (size_t)col*C_DIM + head*HDIM;
    f32x2 acc = {0.f, 0.f};
    #pragma unroll
    for (int q=0;q<4;++q){
      i32x4 kv = *(const i32x4*)(krow + q*8);
      #pragma unroll
      for (int j=0;j<4;++j){
        unsigned u = (unsigned)kv[j];
        f32x2 p; p.x = __uint_as_float(u << 16); p.y = __uint_as_float(u & 0xFFFF0000u);
        acc += p * q2[q*4+j];
      }
    }
    float s = acc.x + acc.y;
    lds_e[prow][sub] = expm1f(s*SCALE);
    lds_idx[prow][sub] = col;
  }
  __syncthreads();

  // ---- phase 3: closed-form masked softmax PV: 32 rows x 32 dims ----
  #pragma unroll
  for (int it=0; it<4; ++it){
    int flat = it*256 + tid;
    int rl = flat >> 5, d = flat & 31;
    float num = sumv[head*HDIM + d];
    float den = 4096.0f;
    #pragma unroll
    for (int j=0;j<8;++j){
      float e = lds_e[rl][j];
      den += e;
      num += e * v[(size_t)lds_idx[rl][j]*C_DIM + head*HDIM + d];
    }
    outbf[(size_t)(row0 + rl)*C_DIM + head*HDIM + d] = f2bf(num/den);
  }
}

// ---------------- LDS-tiled grouped dwconv 3x3 & 5x5 -> cat[p][2048] bf16 ----------------
__global__ __launch_bounds__(256) void dwconv_tiled(const float* __restrict__ img, // h2T [256][4096]
    const float* __restrict__ w3, const float* __restrict__ b3,
    const float* __restrict__ w5, const float* __restrict__ b5,
    unsigned short* __restrict__ cat)
{
  __shared__ float tile[8][513];
  int ic0 = blockIdx.x * 8;
  int py0 = blockIdx.y * 4;
  int tid = threadIdx.x;

  #pragma unroll
  for (int i = 0; i < 16; ++i){
    int idx = i*256 + tid;
    int ch  = idx >> 9;
    int rem = idx & 511;
    int ry  = rem >> 6, x = rem & 63;
    int y   = py0 - 2 + ry;
    float v = (y >= 0 && y < 64) ? img[(size_t)(ic0+ch)*4096 + y*64 + x] : 0.f;
    tile[ch][ry*64 + x] = v;
  }
  __syncthreads();

  int o_l  = tid & 31;
  int p_l  = tid >> 5;
  int ic_l = o_l >> 2;
  int o3   = ic0*4 + o_l;
  const float* pl = tile[ic_l];

  float W3[9], W5[25];
  #pragma unroll
  for (int i=0;i<9;++i)  W3[i] = w3[o3*9+i];
  #pragma unroll
  for (int i=0;i<25;++i) W5[i] = w5[o3*25+i];
  float bb3 = b3[o3], bb5 = b5[o3];

  #pragma unroll 4
  for (int it = 0; it < 32; ++it){
    int pp = it*8 + p_l;
    int ly = (pp >> 6) + 2;
    int x  = pp & 63;
    float a3 = bb3, a5 = bb5;
    #pragma unroll
    for (int dy=-2; dy<=2; ++dy){
      #pragma unroll
      for (int dx=-2; dx<=2; ++dx){
        int xx = x + dx;
        float iv = (xx >= 0 && xx < 64) ? pl[(ly+dy)*64 + xx] : 0.f;
        a5 += W5[(dy+2)*5 + dx+2] * iv;
        if (dy>=-1 && dy<=1 && dx>=-1 && dx<=1)
          a3 += W3[(dy+1)*3 + dx+1] * iv;
      }
    }
    int p = (py0 + (pp>>6))*64 + x;
    cat[(size_t)p*2048 + o3]        = f2bf(fmaxf(a3, 0.f));
    cat[(size_t)p*2048 + 1024 + o3] = f2bf(fmaxf(a5, 0.f));
  }
}

extern "C" void kernel_launch(void* const* d_in, const int* in_sizes, int n_in,
                              void* d_out, int out_size, void* d_ws, size_t ws_size,
                              hipStream_t stream)
{
  (void)in_sizes; (void)n_in; (void)out_size; (void)ws_size;
  const float* x      = (const float*)d_in[0];
  const float* ln1_g  = (const float*)d_in[3];
  const float* ln1_b  = (const float*)d_in[4];
  const float* q_w    = (const float*)d_in[5];
  const float* q_b    = (const float*)d_in[6];
  const float* kv_w   = (const float*)d_in[7];
  const float* kv_b   = (const float*)d_in[8];
  const float* proj_w = (const float*)d_in[9];
  const float* proj_b = (const float*)d_in[10];
  const float* ln2_g  = (const float*)d_in[11];
  const float* ln2_b  = (const float*)d_in[12];
  const float* w3     = (const float*)d_in[13];
  const float* b3     = (const float*)d_in[14];
  const float* w5     = (const float*)d_in[15];
  const float* b5     = (const float*)d_in[16];
  const float* w1     = (const float*)d_in[17];
  const float* b1     = (const float*)d_in[18];
  float* out = (float*)d_out;
  char* ws = (char*)d_ws;

  unsigned short* wAll = (unsigned short*)(ws + 0x0);       // 384 KB: q(256)|k,v(512) rows x 256
  unsigned short* pwT  = (unsigned short*)(ws + 0x60000);   // 128 KB
  unsigned short* w1bf = (unsigned short*)(ws + 0x80000);   // 1 MB
  unsigned short* hbf  = (unsigned short*)(ws + 0x180000);  // 2 MB
  unsigned short* qbf  = (unsigned short*)(ws + 0x380000);  // 2 MB
  unsigned short* kbf  = (unsigned short*)(ws + 0x580000);  // 2 MB
  float*          vbuf = (float*)(ws + 0x780000);           // 4 MB
  unsigned short* obf  = (unsigned short*)(ws + 0xB80000);  // 2 MB
  float*          x2   = (float*)(ws + 0xD80000);           // 4 MB
  float*          sumv = (float*)(ws + 0x1180000);          // 1 KB
  float*          part = (float*)(ws + 0x1190000);          // 64 KB
  unsigned short* kpack= (unsigned short*)(ws + 0x180000);  // 2 MB, reuse hbf (dead after qkv)
  float*          h2   = (float*)(ws + 0x180000);           // 4 MB, reuse hbf+qbf after attn
  float*          h2T  = (float*)(ws + 0x580000);           // 4 MB, reuse kbf+vbuf-lo after attn
  float*          pbuf = (float*)(ws + 0x180000);           // 8 MB, reuse h2/h2T after dwconv
  unsigned short* cat  = (unsigned short*)(ws + 0x1200000); // 16 MB -> end 0x2200000

  dim3 b256(256), b128(128);

  // weight prep
  cvt_bf<<<dim3(2048), b256, 0, stream>>>(w1, w1bf, 256*2048);
  transpose_k<<<dim3(4,4), b256, 0, stream>>>(q_w,   nullptr, wAll,  256, 256);
  transpose_k<<<dim3(8,4), b256, 0, stream>>>(kv_w,  nullptr, wAll + 256*256, 256, 512);
  transpose_k<<<dim3(4,4), b256, 0, stream>>>(proj_w,nullptr, pwT,  256, 256);

  // attention branch
  ln_kernel<1><<<dim3(4096), b256, 0, stream>>>(x, ln1_g, ln1_b, nullptr, hbf);
  gemm_qkv<<<dim3(128,24), b128, 0, stream>>>(hbf, wAll, q_b, kv_b, qbf, kbf, vbuf);
  repack_k<<<dim3(2048), b256, 0, stream>>>(kbf, kpack);    // overwrites hbf region (now dead)
  colsum_part <<<dim3(64), b256, 0, stream>>>(vbuf, part);
  colsum_final<<<dim3(1),  b256, 0, stream>>>(part, sumv);
  attn_kernel<<<dim3(128,8), b256, 0, stream>>>(qbf, kbf, kpack, vbuf, sumv, obf);
  gemm16x32<0><<<dim3(128,8,1), b128, 0, stream>>>(obf, pwT, proj_b, x, x2, nullptr, 256, 256, nullptr);

  // MSFN branch
  ln_kernel<0><<<dim3(4096), b256, 0, stream>>>(x2, ln2_g, ln2_b, h2, nullptr);
  transpose_k<<<dim3(4,64), b256, 0, stream>>>(h2, h2T, nullptr, 4096, 256);
  dwconv_tiled<<<dim3(32,16), b256, 0, stream>>>(h2T, w3, b3, w5, b5, cat);
  gemm16x32<0><<<dim3(128,8,2), b128, 0, stream>>>(cat, w1bf, nullptr, nullptr, nullptr, nullptr, 2048, 1024, pbuf);
  reduce_conv1<<<dim3(1024), b256, 0, stream>>>(pbuf, b1, x2, out);
}